// Round 6
// baseline (21.554 us; speedup 1.0000x reference)
//
#include <hip/hip_runtime.h>

#define NT   1024   // threads per block (16 waves)
#define NBLK 256    // fixed grid: 8 leaf groups x 32 blocks (counter math relies on this)
#define ROWS 8      // rows register-blocked per group

__device__ __forceinline__ float pair_loss(float tt, float pp, float tj, float pj, float margin) {
    float td = tt - tj;
    float pd = pp - pj;
    float cs = copysignf(1.0f, td);            // ties -> +/-1; off-diagonal ties have ~0 probability
    return fmaxf(fmaf(-cs, pd, margin), 0.0f);
}

__device__ __forceinline__ void do_j(float tj, float pj, const float* tg, const float* pg,
                                     float margin, float* av) {
    #pragma unroll
    for (int k = 0; k < ROWS; ++k) av[k] += pair_loss(tg[k], pg[k], tj, pj, margin);
}

__global__ __launch_bounds__(NT, 4)
void fused_kernel(const float* __restrict__ preds, const float* __restrict__ targets,
                  double* __restrict__ partials,      // [NBLK]
                  unsigned int* __restrict__ leaf,    // [8]  monotonically counted, used mod 32
                  unsigned int* __restrict__ root,    // [1]  used mod 8
                  float* __restrict__ out, int N, double inv_pairs)
{
    const int tid = threadIdx.x, lane = tid & 63, wave = tid >> 6;
    const int bid = (int)blockIdx.x;
    __shared__ double redd[2 * (NT / 64)];
    __shared__ float smargin;
    __shared__ int sflag;

    // ---- per-block redundant margin = 0.25 * std(targets, ddof=1) ----
    {
        double s = 0.0, s2 = 0.0;
        const int n4 = N >> 2;
        const float4* t4 = (const float4*)targets;
        for (int i = tid; i < n4; i += NT) {
            float4 v = t4[i];
            s  += (double)v.x + (double)v.y + (double)v.z + (double)v.w;
            s2 += (double)v.x * v.x + (double)v.y * v.y + (double)v.z * v.z + (double)v.w * v.w;
        }
        for (int i = (n4 << 2) + tid; i < N; i += NT) { float t = targets[i]; s += t; s2 += (double)t * t; }
        #pragma unroll
        for (int off = 32; off; off >>= 1) { s += __shfl_down(s, off, 64); s2 += __shfl_down(s2, off, 64); }
        if (lane == 0) { redd[wave] = s; redd[NT / 64 + wave] = s2; }
        __syncthreads();
        if (tid == 0) {
            double S = 0.0, S2 = 0.0;
            for (int w = 0; w < NT / 64; ++w) { S += redd[w]; S2 += redd[NT / 64 + w]; }
            double mean = S / (double)N;
            double var  = (S2 - (double)N * mean * mean) / (double)(N - 1);
            smargin = (float)(0.25 * sqrt(var > 0.0 ? var : 0.0));
        }
        __syncthreads();
    }
    const float margin = smargin;

    // ---- all-pairs, 8-row register blocking, paired groups (g, G-1-g) for uniform work ----
    const int G = N >> 3;                 // groups of ROWS rows
    const int P = G >> 1;                 // group pairs

    float av[ROWS];
    #pragma unroll
    for (int k = 0; k < ROWS; ++k) av[k] = 0.0f;
    float extra = 0.0f;

    for (int p = bid; p < P; p += NBLK) {
        #pragma unroll
        for (int side = 0; side < 2; ++side) {
            const int gg = side ? (G - 1 - p) : p;
            const int i0 = gg << 3;
            float tg[ROWS], pg[ROWS];
            #pragma unroll
            for (int k = 0; k < ROWS; ++k) { tg[k] = targets[i0 + k]; pg[k] = preds[i0 + k]; }

            // intra-group 8x8 strict upper triangle (28 pairs), exact tie semantics
            if (tid < 64) {
                int ii = tid >> 3, jj = tid & 7;
                if (ii < jj) {
                    float td = tg[ii] - tg[jj], pd = pg[ii] - pg[jj];
                    float cs = (td > 0.0f) ? 1.0f : ((td < 0.0f) ? -1.0f : 0.0f);
                    extra += fmaxf(fmaf(-cs, pd, margin), 0.0f);
                }
            }

            const int lo = i0 + ROWS;          // multiple of 8 -> float4 aligned
            const int len = N - lo;
            const int len4 = len >> 2;
            const float4* tj4 = (const float4*)(targets + lo);
            const float4* pj4 = (const float4*)(preds + lo);
            for (int idx = tid; idx < len4; idx += NT) {
                float4 tv = tj4[idx];
                float4 pv = pj4[idx];
                do_j(tv.x, pv.x, tg, pg, margin, av);
                do_j(tv.y, pv.y, tg, pg, margin, av);
                do_j(tv.z, pv.z, tg, pg, margin, av);
                do_j(tv.w, pv.w, tg, pg, margin, av);
            }
            for (int j = lo + (len4 << 2) + tid; j < N; j += NT) {   // dead when N % 4 == 0
                do_j(targets[j], preds[j], tg, pg, margin, av);
            }
        }
    }

    // ---- leftovers for general N (dead when N % 16 == 0) ----
    if (bid == 0) {
        if (G & 1) {
            const int i0 = (G >> 1) << 3;
            for (int k = 0; k < ROWS && i0 + k < N; ++k) {
                const int i = i0 + k;
                for (int j = i + 1 + tid; j < N; j += NT) {
                    float td = targets[i] - targets[j], pd = preds[i] - preds[j];
                    float cs = (td > 0.0f) ? 1.0f : ((td < 0.0f) ? -1.0f : 0.0f);
                    extra += fmaxf(fmaf(-cs, pd, margin), 0.0f);
                }
            }
        }
        for (int i = G << 3; i < N; ++i) {
            for (int j = i + 1 + tid; j < N; j += NT) {
                float td = targets[i] - targets[j], pd = preds[i] - preds[j];
                float cs = (td > 0.0f) ? 1.0f : ((td < 0.0f) ? -1.0f : 0.0f);
                extra += fmaxf(fmaf(-cs, pd, margin), 0.0f);
            }
        }
    }

    // ---- block reduce ----
    double tot = (double)extra;
    #pragma unroll
    for (int k = 0; k < ROWS; ++k) tot += (double)av[k];
    #pragma unroll
    for (int off = 32; off; off >>= 1) tot += __shfl_down(tot, off, 64);
    __syncthreads();                       // margin-phase redd reads done; safe to reuse
    if (lane == 0) redd[wave] = tot;
    __syncthreads();

    // ---- publish partial + two-level last-arriver tree (no fences, no memset needed) ----
    if (tid == 0) {
        double bt = 0.0;
        for (int w = 0; w < NT / 64; ++w) bt += redd[w];
        __hip_atomic_store(&partials[bid], bt, __ATOMIC_RELAXED, __HIP_MEMORY_SCOPE_AGENT);
        const unsigned g = (unsigned)bid >> 5;                  // 8 groups of 32 blocks
        unsigned lv = __hip_atomic_fetch_add(&leaf[g], 1u, __ATOMIC_ACQ_REL, __HIP_MEMORY_SCOPE_AGENT);
        int f = 0;
        if ((lv & 31u) == 31u) {                                // last of this leaf (mod works across replays)
            unsigned rv = __hip_atomic_fetch_add(root, 1u, __ATOMIC_ACQ_REL, __HIP_MEMORY_SCOPE_AGENT);
            if ((rv & 7u) == 7u) f = 1;                         // last leaf overall -> finalizer
        }
        sflag = f;
    }
    __syncthreads();

    if (sflag != 0 && tid < 64) {
        double s = 0.0;
        for (int i = lane; i < NBLK; i += 64)
            s += __hip_atomic_load(&partials[i], __ATOMIC_RELAXED, __HIP_MEMORY_SCOPE_AGENT);
        #pragma unroll
        for (int off = 32; off; off >>= 1) s += __shfl_down(s, off, 64);
        if (lane == 0) out[0] = (float)(s * inv_pairs);
    }
}

extern "C" void kernel_launch(void* const* d_in, const int* in_sizes, int n_in,
                              void* d_out, int out_size, void* d_ws, size_t ws_size,
                              hipStream_t stream) {
    const float* preds   = (const float*)d_in[0];
    const float* targets = (const float*)d_in[1];
    float* out = (float*)d_out;
    int N = in_sizes[0];

    double*       partials = (double*)d_ws;                         // 256 * 8 B
    unsigned int* leaf     = (unsigned int*)((char*)d_ws + NBLK * sizeof(double)); // 8 * 4 B
    unsigned int* root     = leaf + 8;                              // 1 * 4 B

    const double inv_pairs = 2.0 / ((double)N * (double)(N - 1));
    fused_kernel<<<NBLK, NT, 0, stream>>>(preds, targets, partials, leaf, root, out, N, inv_pairs);
}

// Round 8
// 20.690 us; speedup vs baseline: 1.0418x; 1.0418x over previous
//
#include <hip/hip_runtime.h>

#define NT    256   // threads per pair-kernel block
#define SPLIT 2     // sub-blocks per row-group pair
#define ROWS  8     // rows register-blocked per group

__device__ __forceinline__ float pair_loss(float tt, float pp, float tj, float pj, float margin) {
    float td = tt - tj;
    float pd = pp - pj;
    float cs = copysignf(1.0f, td);            // ties -> +/-1; off-diagonal ties have ~0 probability
    return fmaxf(fmaf(-cs, pd, margin), 0.0f);
}

__device__ __forceinline__ void do_j(float tj, float pj, const float* tg, const float* pg,
                                     float margin, float* av) {
    #pragma unroll
    for (int k = 0; k < ROWS; ++k) av[k] += pair_loss(tg[k], pg[k], tj, pj, margin);
}

// ---- kernel 1: margin = 0.25 * std(targets, ddof=1), computed ONCE ----
__global__ __launch_bounds__(1024)
void margin_kernel(const float* __restrict__ targets, int N, float* __restrict__ margin_out)
{
    const int tid = threadIdx.x, lane = tid & 63, wave = tid >> 6;
    __shared__ double redd[2 * 16];
    double s = 0.0, s2 = 0.0;
    const int n4 = N >> 2;
    const float4* t4 = (const float4*)targets;
    for (int i = tid; i < n4; i += 1024) {
        float4 v = t4[i];
        s  += (double)v.x + (double)v.y + (double)v.z + (double)v.w;
        s2 += (double)v.x * v.x + (double)v.y * v.y + (double)v.z * v.z + (double)v.w * v.w;
    }
    for (int i = (n4 << 2) + tid; i < N; i += 1024) { float t = targets[i]; s += t; s2 += (double)t * t; }
    #pragma unroll
    for (int off = 32; off; off >>= 1) { s += __shfl_down(s, off, 64); s2 += __shfl_down(s2, off, 64); }
    if (lane == 0) { redd[wave] = s; redd[16 + wave] = s2; }
    __syncthreads();
    if (tid == 0) {
        double S = 0.0, S2 = 0.0;
        const int nw = (int)(blockDim.x >> 6);
        for (int w = 0; w < nw; ++w) { S += redd[w]; S2 += redd[16 + w]; }
        double mean = S / (double)N;
        double var  = (S2 - (double)N * mean * mean) / (double)(N - 1);
        margin_out[0] = (float)(0.25 * sqrt(var > 0.0 ? var : 0.0));
    }
}

// ---- kernel 2: all pairs, plain partial stores (combined by kernel 3) ----
__global__ __launch_bounds__(NT, 4)
void pair_kernel(const float* __restrict__ preds, const float* __restrict__ targets,
                 const float* __restrict__ margin_p,
                 double* __restrict__ partials, int N)
{
    const int tid = threadIdx.x, lane = tid & 63, wave = tid >> 6;
    __shared__ double redd[NT / 64];

    const float margin = margin_p[0];

    const int G = N >> 3;                 // groups of ROWS rows
    const int P = G >> 1;                 // group pairs (g, G-1-g): uniform combined work
    const int NB = (int)gridDim.x;        // multiple of SPLIT
    const int sub = (int)(blockIdx.x & (SPLIT - 1));
    const int pairblk = (int)(blockIdx.x >> 1);       // / SPLIT
    const int PSTRIDE = NB >> 1;                      // / SPLIT

    float av[ROWS];
    #pragma unroll
    for (int k = 0; k < ROWS; ++k) av[k] = 0.0f;
    float extra = 0.0f;

    for (int p = pairblk; p < P; p += PSTRIDE) {
        #pragma unroll
        for (int side = 0; side < 2; ++side) {
            const int gg = side ? (G - 1 - p) : p;
            const int i0 = gg << 3;
            float tg[ROWS], pg[ROWS];
            #pragma unroll
            for (int k = 0; k < ROWS; ++k) { tg[k] = targets[i0 + k]; pg[k] = preds[i0 + k]; }

            // intra-group 8x8 strict upper triangle (28 pairs), exact tie semantics
            if (sub == side && tid < 64) {
                int ii = tid >> 3, jj = tid & 7;
                if (ii < jj) {
                    float td = tg[ii] - tg[jj], pd = pg[ii] - pg[jj];
                    float cs = (td > 0.0f) ? 1.0f : ((td < 0.0f) ? -1.0f : 0.0f);
                    extra += fmaxf(fmaf(-cs, pd, margin), 0.0f);
                }
            }

            const int lo = i0 + ROWS;          // multiple of 8 -> float4 aligned
            const int len = N - lo;
            const int len4 = len >> 2;
            const float4* tj4 = (const float4*)(targets + lo);
            const float4* pj4 = (const float4*)(preds + lo);
            for (int idx = sub * NT + tid; idx < len4; idx += NT * SPLIT) {
                float4 tv = tj4[idx];
                float4 pv = pj4[idx];
                do_j(tv.x, pv.x, tg, pg, margin, av);
                do_j(tv.y, pv.y, tg, pg, margin, av);
                do_j(tv.z, pv.z, tg, pg, margin, av);
                do_j(tv.w, pv.w, tg, pg, margin, av);
            }
            for (int j = lo + (len4 << 2) + sub * NT + tid; j < N; j += NT * SPLIT) {
                do_j(targets[j], preds[j], tg, pg, margin, av);   // dead when N % 4 == 0
            }
        }
    }

    // ---- leftovers for general N (dead when N % 16 == 0) ----
    if (pairblk == 0) {
        if (G & 1) {
            const int i0 = (G >> 1) << 3;
            for (int k = 0; k < ROWS && i0 + k < N; ++k) {
                const int i = i0 + k;
                for (int j = i + 1 + sub * NT + tid; j < N; j += NT * SPLIT) {
                    float td = targets[i] - targets[j], pd = preds[i] - preds[j];
                    float cs = (td > 0.0f) ? 1.0f : ((td < 0.0f) ? -1.0f : 0.0f);
                    extra += fmaxf(fmaf(-cs, pd, margin), 0.0f);
                }
            }
        }
        for (int i = G << 3; i < N; ++i) {
            for (int j = i + 1 + sub * NT + tid; j < N; j += NT * SPLIT) {
                float td = targets[i] - targets[j], pd = preds[i] - preds[j];
                float cs = (td > 0.0f) ? 1.0f : ((td < 0.0f) ? -1.0f : 0.0f);
                extra += fmaxf(fmaf(-cs, pd, margin), 0.0f);
            }
        }
    }

    // ---- block reduce (f64), plain store; next dispatch reads it (safe) ----
    double tot = (double)extra;
    #pragma unroll
    for (int k = 0; k < ROWS; ++k) tot += (double)av[k];
    #pragma unroll
    for (int off = 32; off; off >>= 1) tot += __shfl_down(tot, off, 64);
    if (lane == 0) redd[wave] = tot;
    __syncthreads();
    if (tid == 0) {
        double bt = 0.0;
        for (int w = 0; w < NT / 64; ++w) bt += redd[w];
        partials[blockIdx.x] = bt;
    }
}

// ---- kernel 3: sum partials -> out ----
__global__ __launch_bounds__(NT)
void finalize_kernel(const double* __restrict__ partials, int nparts,
                     float* __restrict__ out, double inv_pairs)
{
    __shared__ double red[NT / 64];
    const int tid = threadIdx.x, lane = tid & 63, wave = tid >> 6;
    double s = 0.0;
    for (int i = tid; i < nparts; i += NT) s += partials[i];
    #pragma unroll
    for (int off = 32; off; off >>= 1) s += __shfl_down(s, off, 64);
    if (lane == 0) red[wave] = s;
    __syncthreads();
    if (tid == 0) {
        double t = 0.0;
        for (int w = 0; w < NT / 64; ++w) t += red[w];
        out[0] = (float)(t * inv_pairs);
    }
}

extern "C" void kernel_launch(void* const* d_in, const int* in_sizes, int n_in,
                              void* d_out, int out_size, void* d_ws, size_t ws_size,
                              hipStream_t stream) {
    const float* preds   = (const float*)d_in[0];
    const float* targets = (const float*)d_in[1];
    float* out = (float*)d_out;
    int N = in_sizes[0];

    double* partials = (double*)d_ws;                       // up to 1024 * 8 B
    float*  marg     = (float*)((char*)d_ws + 1024 * 8);    // 4 B

    const int G = N >> 3;
    const int P = G >> 1;
    int NB = (P > 0 ? P : 1) * SPLIT;                       // N=8192 -> 512*2 = 1024 blocks
    if (NB > 1024) NB = 1024;

    const double inv_pairs = 2.0 / ((double)N * (double)(N - 1));
    margin_kernel<<<1, 1024, 0, stream>>>(targets, N, marg);
    pair_kernel<<<NB, NT, 0, stream>>>(preds, targets, marg, partials, N);
    finalize_kernel<<<1, NT, 0, stream>>>(partials, NB, out, inv_pairs);
}

// Round 9
// 17.449 us; speedup vs baseline: 1.2352x; 1.1857x over previous
//
#include <hip/hip_runtime.h>

#define NT    256   // threads per pair-kernel block
#define SPLIT 2     // sub-blocks per row-group pair
#define ROWS  8     // rows register-blocked per group

__device__ __forceinline__ float pair_loss(float tt, float pp, float tj, float pj, float margin) {
    float td = tt - tj;
    float pd = pp - pj;
    float cs = copysignf(1.0f, td);            // ties -> +/-1; off-diagonal ties have ~0 probability
    return fmaxf(fmaf(-cs, pd, margin), 0.0f);
}

__device__ __forceinline__ void do_j(float tj, float pj, const float* tg, const float* pg,
                                     float margin, float* av) {
    #pragma unroll
    for (int k = 0; k < ROWS; ++k) av[k] += pair_loss(tg[k], pg[k], tj, pj, margin);
}

// ---- kernel 1: all pairs; cheap per-block f32 margin prologue; plain partial stores ----
__global__ __launch_bounds__(NT, 4)
void pair_kernel(const float* __restrict__ preds, const float* __restrict__ targets,
                 double* __restrict__ partials, int N)
{
    const int tid = threadIdx.x, lane = tid & 63, wave = tid >> 6;
    __shared__ float  sred[2 * (NT / 64)];
    __shared__ double redd[NT / 64];

    // ---- lean f32 margin = 0.25 * std(targets, ddof=1), redundant per block ----
    float margin;
    {
        float s = 0.0f, s2 = 0.0f;
        const int n4 = N >> 2;
        const float4* t4 = (const float4*)targets;
        for (int i = tid; i < n4; i += NT) {
            float4 v = t4[i];
            s  += v.x + v.y + v.z + v.w;
            s2 += v.x * v.x + v.y * v.y + v.z * v.z + v.w * v.w;
        }
        for (int i = (n4 << 2) + tid; i < N; i += NT) { float t = targets[i]; s += t; s2 += t * t; }
        #pragma unroll
        for (int off = 32; off; off >>= 1) { s += __shfl_xor(s, off, 64); s2 += __shfl_xor(s2, off, 64); }
        if (lane == 0) { sred[wave] = s; sred[NT / 64 + wave] = s2; }
        __syncthreads();
        float S = 0.0f, S2 = 0.0f;
        #pragma unroll
        for (int w = 0; w < NT / 64; ++w) { S += sred[w]; S2 += sred[NT / 64 + w]; }
        float mean = S / (float)N;
        float var  = (S2 - (float)N * mean * mean) / (float)(N - 1);
        margin = 0.25f * sqrtf(fmaxf(var, 0.0f));
    }

    const int G = N >> 3;                 // groups of ROWS rows
    const int P = G >> 1;                 // group pairs (g, G-1-g): uniform combined work
    const int NB = (int)gridDim.x;        // multiple of SPLIT
    const int sub = (int)(blockIdx.x & (SPLIT - 1));
    const int pairblk = (int)(blockIdx.x >> 1);       // / SPLIT
    const int PSTRIDE = NB >> 1;                      // / SPLIT

    float av[ROWS];
    #pragma unroll
    for (int k = 0; k < ROWS; ++k) av[k] = 0.0f;
    float extra = 0.0f;

    for (int p = pairblk; p < P; p += PSTRIDE) {
        #pragma unroll
        for (int side = 0; side < 2; ++side) {
            const int gg = side ? (G - 1 - p) : p;
            const int i0 = gg << 3;
            float tg[ROWS], pg[ROWS];
            #pragma unroll
            for (int k = 0; k < ROWS; ++k) { tg[k] = targets[i0 + k]; pg[k] = preds[i0 + k]; }

            // intra-group 8x8 strict upper triangle (28 pairs), exact tie semantics
            if (sub == side && tid < 64) {
                int ii = tid >> 3, jj = tid & 7;
                if (ii < jj) {
                    float td = tg[ii] - tg[jj], pd = pg[ii] - pg[jj];
                    float cs = (td > 0.0f) ? 1.0f : ((td < 0.0f) ? -1.0f : 0.0f);
                    extra += fmaxf(fmaf(-cs, pd, margin), 0.0f);
                }
            }

            const int lo = i0 + ROWS;          // multiple of 8 -> float4 aligned
            const int len = N - lo;
            const int len4 = len >> 2;
            const float4* tj4 = (const float4*)(targets + lo);
            const float4* pj4 = (const float4*)(preds + lo);
            for (int idx = sub * NT + tid; idx < len4; idx += NT * SPLIT) {
                float4 tv = tj4[idx];
                float4 pv = pj4[idx];
                do_j(tv.x, pv.x, tg, pg, margin, av);
                do_j(tv.y, pv.y, tg, pg, margin, av);
                do_j(tv.z, pv.z, tg, pg, margin, av);
                do_j(tv.w, pv.w, tg, pg, margin, av);
            }
            for (int j = lo + (len4 << 2) + sub * NT + tid; j < N; j += NT * SPLIT) {
                do_j(targets[j], preds[j], tg, pg, margin, av);   // dead when N % 4 == 0
            }
        }
    }

    // ---- leftovers for general N (dead when N % 16 == 0) ----
    if (pairblk == 0) {
        if (G & 1) {
            const int i0 = (G >> 1) << 3;
            for (int k = 0; k < ROWS && i0 + k < N; ++k) {
                const int i = i0 + k;
                for (int j = i + 1 + sub * NT + tid; j < N; j += NT * SPLIT) {
                    float td = targets[i] - targets[j], pd = preds[i] - preds[j];
                    float cs = (td > 0.0f) ? 1.0f : ((td < 0.0f) ? -1.0f : 0.0f);
                    extra += fmaxf(fmaf(-cs, pd, margin), 0.0f);
                }
            }
        }
        for (int i = G << 3; i < N; ++i) {
            for (int j = i + 1 + sub * NT + tid; j < N; j += NT * SPLIT) {
                float td = targets[i] - targets[j], pd = preds[i] - preds[j];
                float cs = (td > 0.0f) ? 1.0f : ((td < 0.0f) ? -1.0f : 0.0f);
                extra += fmaxf(fmaf(-cs, pd, margin), 0.0f);
            }
        }
    }

    // ---- block reduce (f64), plain store; next dispatch reads it (safe) ----
    double tot = (double)extra;
    #pragma unroll
    for (int k = 0; k < ROWS; ++k) tot += (double)av[k];
    #pragma unroll
    for (int off = 32; off; off >>= 1) tot += __shfl_down(tot, off, 64);
    __syncthreads();                       // sred reads done; redd aliases fresh space anyway
    if (lane == 0) redd[wave] = tot;
    __syncthreads();
    if (tid == 0) {
        double bt = 0.0;
        for (int w = 0; w < NT / 64; ++w) bt += redd[w];
        partials[blockIdx.x] = bt;
    }
}

// ---- kernel 2: sum partials -> out ----
__global__ __launch_bounds__(NT)
void finalize_kernel(const double* __restrict__ partials, int nparts,
                     float* __restrict__ out, double inv_pairs)
{
    __shared__ double red[NT / 64];
    const int tid = threadIdx.x, lane = tid & 63, wave = tid >> 6;
    double s = 0.0;
    for (int i = tid; i < nparts; i += NT) s += partials[i];
    #pragma unroll
    for (int off = 32; off; off >>= 1) s += __shfl_down(s, off, 64);
    if (lane == 0) red[wave] = s;
    __syncthreads();
    if (tid == 0) {
        double t = 0.0;
        for (int w = 0; w < NT / 64; ++w) t += red[w];
        out[0] = (float)(t * inv_pairs);
    }
}

extern "C" void kernel_launch(void* const* d_in, const int* in_sizes, int n_in,
                              void* d_out, int out_size, void* d_ws, size_t ws_size,
                              hipStream_t stream) {
    const float* preds   = (const float*)d_in[0];
    const float* targets = (const float*)d_in[1];
    float* out = (float*)d_out;
    int N = in_sizes[0];

    double* partials = (double*)d_ws;                       // up to 1024 * 8 B

    const int G = N >> 3;
    const int P = G >> 1;
    int NB = (P > 0 ? P : 1) * SPLIT;                       // N=8192 -> 512*2 = 1024 blocks
    if (NB > 1024) NB = 1024;

    const double inv_pairs = 2.0 / ((double)N * (double)(N - 1));
    pair_kernel<<<NB, NT, 0, stream>>>(preds, targets, partials, N);
    finalize_kernel<<<1, NT, 0, stream>>>(partials, NB, out, inv_pairs);
}